// Round 1
// baseline (1385.898 us; speedup 1.0000x reference)
//
#include <hip/hip_runtime.h>

#define DCH 64
#define NEG 0.2f

typedef float fx4 __attribute__((ext_vector_type(4)));
typedef short short8 __attribute__((ext_vector_type(8)));

__device__ __forceinline__ unsigned short f2bf(float f) {
    unsigned int u = __builtin_bit_cast(unsigned int, f);
    u += 0x7fffu + ((u >> 16) & 1u);   // round-to-nearest-even
    return (unsigned short)(u >> 16);
}

__device__ __forceinline__ short8 pack_bf16x8(fx4 a, fx4 b) {
    short8 r;
    r[0] = (short)f2bf(a[0]); r[1] = (short)f2bf(a[1]);
    r[2] = (short)f2bf(a[2]); r[3] = (short)f2bf(a[3]);
    r[4] = (short)f2bf(b[0]); r[5] = (short)f2bf(b[1]);
    r[6] = (short)f2bf(b[2]); r[7] = (short)f2bf(b[3]);
    return r;
}

// ---------------- CSR build ----------------
__global__ void k_zero(int* __restrict__ p, int n) {
    int i = blockIdx.x * blockDim.x + threadIdx.x;
    if (i < n) p[i] = 0;
}

__global__ void k_count(const int* __restrict__ ei, int* __restrict__ deg, int E) {
    int e = blockIdx.x * blockDim.x + threadIdx.x;
    if (e < E) atomicAdd(&deg[ei[E + e]], 1);
}

// block scans 1024 elements (256 threads x 4)
__global__ void k_scan1(const int* __restrict__ deg, int* __restrict__ rowptr,
                        int* __restrict__ bsum, int n) {
    __shared__ int s[256];
    int t = threadIdx.x;
    int base = blockIdx.x * 1024 + t * 4;
    int v[4]; int sum = 0;
    #pragma unroll
    for (int j = 0; j < 4; j++) {
        int idx = base + j;
        v[j] = (idx < n) ? deg[idx] : 0;
        sum += v[j];
    }
    s[t] = sum;
    __syncthreads();
    for (int o = 1; o < 256; o <<= 1) {
        int add = (t >= o) ? s[t - o] : 0;
        __syncthreads();
        s[t] += add;
        __syncthreads();
    }
    int excl = s[t] - sum;
    if (t == 255) bsum[blockIdx.x] = s[255];
    int run = excl;
    #pragma unroll
    for (int j = 0; j < 4; j++) {
        int idx = base + j;
        if (idx < n) rowptr[idx] = run;
        run += v[j];
    }
}

__global__ void k_scan2(int* __restrict__ bsum, int nb) {
    int run = 0;
    for (int i = 0; i < nb; i++) { int t = bsum[i]; bsum[i] = run; run += t; }
}

__global__ void k_scan3(int* __restrict__ rowptr, const int* __restrict__ bsum,
                        int n, int E) {
    int i = blockIdx.x * blockDim.x + threadIdx.x;
    if (i < n) rowptr[i] += bsum[i >> 10];
    if (i == 0) rowptr[n] = E;
}

__global__ void k_fill(const int* __restrict__ ei, const int* __restrict__ rowptr,
                       int* __restrict__ cnt, int* __restrict__ csrc,
                       int* __restrict__ ceid, int E) {
    int e = blockIdx.x * blockDim.x + threadIdx.x;
    if (e < E) {
        int t = ei[E + e];
        int p = rowptr[t] + atomicAdd(&cnt[t], 1);
        csrc[p] = ei[e];
        ceid[p] = e;
    }
}

// ---------------- node GEMM: O_m = X @ Wm.T + bm (up to 3 matrices) ----------------
__global__ __launch_bounds__(256) void k_node_gemm(
    const float* __restrict__ X, int nrows,
    const float* __restrict__ W0, const float* __restrict__ b0, float* __restrict__ O0,
    const float* __restrict__ W1, const float* __restrict__ b1, float* __restrict__ O1,
    const float* __restrict__ W2, const float* __restrict__ b2, float* __restrict__ O2)
{
    int wid = (blockIdx.x * blockDim.x + threadIdx.x) >> 6;
    int lane = threadIdx.x & 63;
    int ntiles = (nrows + 63) >> 6;
    if (wid >= ntiles) return;
    int base = wid * 64;
    int l15 = lane & 15, q = lane >> 4;

    // A fragments: A[m][k], m = l15 (+16*mt), k = q*8+j (+32*kt)
    short8 afr[4][2];
    #pragma unroll
    for (int mt = 0; mt < 4; mt++) {
        int row = base + mt * 16 + l15;
        if (row >= nrows) row = nrows - 1;
        const float* xp = X + (size_t)row * DCH + q * 8;
        #pragma unroll
        for (int kt = 0; kt < 2; kt++) {
            fx4 v0 = *(const fx4*)(xp + kt * 32);
            fx4 v1 = *(const fx4*)(xp + kt * 32 + 4);
            afr[mt][kt] = pack_bf16x8(v0, v1);
        }
    }

    const float* Ws[3] = {W0, W1, W2};
    const float* bs[3] = {b0, b1, b2};
    float* Os[3] = {O0, O1, O2};
    int nmat = O2 ? 3 : (O1 ? 2 : 1);

    for (int m = 0; m < nmat; m++) {
        const float* W = Ws[m];
        // B fragments: B[k][n] = W[n][k]; lane holds n=l15(+16*nt), k=q*8+j(+32*kt)
        short8 bfr[4][2];
        #pragma unroll
        for (int nt = 0; nt < 4; nt++) {
            const float* wp = W + (nt * 16 + l15) * DCH + q * 8;
            #pragma unroll
            for (int kt = 0; kt < 2; kt++) {
                fx4 v0 = *(const fx4*)(wp + kt * 32);
                fx4 v1 = *(const fx4*)(wp + kt * 32 + 4);
                bfr[nt][kt] = pack_bf16x8(v0, v1);
            }
        }
        fx4 acc[4][4] = {};
        #pragma unroll
        for (int kt = 0; kt < 2; kt++)
            #pragma unroll
            for (int mt = 0; mt < 4; mt++)
                #pragma unroll
                for (int nt = 0; nt < 4; nt++)
                    acc[mt][nt] = __builtin_amdgcn_mfma_f32_16x16x32_bf16(
                        afr[mt][kt], bfr[nt][kt], acc[mt][nt], 0, 0, 0);

        float bias[4];
        #pragma unroll
        for (int nt = 0; nt < 4; nt++) bias[nt] = bs[m][nt * 16 + l15];
        float* O = Os[m];
        // C/D layout: row = q*4 + r (+16*mt), col = l15 (+16*nt)
        #pragma unroll
        for (int mt = 0; mt < 4; mt++) {
            #pragma unroll
            for (int r = 0; r < 4; r++) {
                int row = base + mt * 16 + q * 4 + r;
                if (row < nrows) {
                    #pragma unroll
                    for (int nt = 0; nt < 4; nt++)
                        O[(size_t)row * DCH + nt * 16 + l15] = acc[mt][nt][r] + bias[nt];
                }
            }
        }
    }
}

// ---------------- edge score: es[e] = exp(att . lrelu(xl[src]+xr[dst]+We@ea)) ----------------
__global__ __launch_bounds__(256) void k_edge_score(
    const float* __restrict__ EA, const int* __restrict__ ei,
    const float* __restrict__ We, const float* __restrict__ att,
    const float* __restrict__ xl, const float* __restrict__ xr,
    float* __restrict__ es, int E)
{
    int wid = (blockIdx.x * blockDim.x + threadIdx.x) >> 6;
    int lane = threadIdx.x & 63;
    int l15 = lane & 15, q = lane >> 4;
    int base = wid * 64;
    if (base >= E) return;

    int s_me = ei[base + lane];
    int t_me = ei[E + base + lane];

    // B fragments from We (same orientation as node GEMM: e[n] = sum_k We[n,k] ea[k])
    short8 bfr[4][2];
    #pragma unroll
    for (int nt = 0; nt < 4; nt++) {
        const float* wp = We + (nt * 16 + l15) * DCH + q * 8;
        #pragma unroll
        for (int kt = 0; kt < 2; kt++) {
            fx4 v0 = *(const fx4*)(wp + kt * 32);
            fx4 v1 = *(const fx4*)(wp + kt * 32 + 4);
            bfr[nt][kt] = pack_bf16x8(v0, v1);
        }
    }
    // A fragments from edge_attr rows
    short8 afr[4][2];
    #pragma unroll
    for (int mt = 0; mt < 4; mt++) {
        const float* p = EA + (size_t)(base + mt * 16 + l15) * DCH + q * 8;
        #pragma unroll
        for (int kt = 0; kt < 2; kt++) {
            fx4 v0 = *(const fx4*)(p + kt * 32);
            fx4 v1 = *(const fx4*)(p + kt * 32 + 4);
            afr[mt][kt] = pack_bf16x8(v0, v1);
        }
    }
    fx4 acc[4][4] = {};
    #pragma unroll
    for (int kt = 0; kt < 2; kt++)
        #pragma unroll
        for (int mt = 0; mt < 4; mt++)
            #pragma unroll
            for (int nt = 0; nt < 4; nt++)
                acc[mt][nt] = __builtin_amdgcn_mfma_f32_16x16x32_bf16(
                    afr[mt][kt], bfr[nt][kt], acc[mt][nt], 0, 0, 0);

    float attr[4];
    #pragma unroll
    for (int nt = 0; nt < 4; nt++) attr[nt] = att[nt * 16 + l15];

    // epilogue: per edge m = mt*16 + q*4 + r; channels n = nt*16 + l15 live in this lane
    #pragma unroll
    for (int mt = 0; mt < 4; mt++) {
        #pragma unroll
        for (int r = 0; r < 4; r++) {
            int m = mt * 16 + q * 4 + r;
            int sm = __shfl(s_me, m);
            int tm = __shfl(t_me, m);
            const float* xls = xl + (size_t)sm * DCH + l15;
            const float* xrt = xr + (size_t)tm * DCH + l15;
            float p = 0.f;
            #pragma unroll
            for (int nt = 0; nt < 4; nt++) {
                float z = acc[mt][nt][r] + xls[nt * 16] + xrt[nt * 16];
                float lr = fmaxf(z, 0.f) + NEG * fminf(z, 0.f);
                p = fmaf(attr[nt], lr, p);
            }
            // reduce over the 16 lanes of this quad-group (cols)
            p += __shfl_xor(p, 1);
            p += __shfl_xor(p, 2);
            p += __shfl_xor(p, 4);
            p += __shfl_xor(p, 8);
            if (l15 == mt * 4 + r) es[base + m] = __expf(p);
        }
    }
}

// ---------------- pull: out[n] = norm(relu(sum es*xl[src]/sum es + bo (+skip))) ----------------
__global__ __launch_bounds__(256) void k_pull(
    const int* __restrict__ rowptr, const int* __restrict__ csrc,
    const int* __restrict__ ceid, const float* __restrict__ es,
    const float* __restrict__ xl, const float* __restrict__ bo,
    const float* __restrict__ skip, float* __restrict__ out, int n_nodes)
{
    int wid = (blockIdx.x * blockDim.x + threadIdx.x) >> 6;
    int lane = threadIdx.x & 63;
    if (wid >= n_nodes) return;
    int r0 = rowptr[wid], r1 = rowptr[wid + 1];
    float acc = 0.f, den = 0.f;
    for (int b = r0; b < r1; b += 64) {
        int cnt = min(64, r1 - b);
        int sj = 0; float wj = 0.f;
        if (lane < cnt) {
            sj = csrc[b + lane];
            wj = es[ceid[b + lane]];
        }
        for (int i = 0; i < cnt; i++) {
            int s = __shfl(sj, i);
            float w = __shfl(wj, i);
            acc = fmaf(w, xl[(size_t)s * DCH + lane], acc);
            den += w;
        }
    }
    float v = acc / (den + 1e-16f) + bo[lane];
    if (skip) v += skip[(size_t)wid * DCH + lane];
    v = fmaxf(v, 0.f);
    // instance norm over the 64 channels (the wave)
    float mu = v;
    #pragma unroll
    for (int o = 1; o < 64; o <<= 1) mu += __shfl_xor(mu, o);
    mu *= (1.f / 64.f);
    float d = v - mu;
    float var = d * d;
    #pragma unroll
    for (int o = 1; o < 64; o <<= 1) var += __shfl_xor(var, o);
    var *= (1.f / 64.f);
    out[(size_t)wid * DCH + lane] = d * rsqrtf(var + 1e-5f);
}

extern "C" void kernel_launch(void* const* d_in, const int* in_sizes, int n_in,
                              void* d_out, int out_size, void* d_ws, size_t ws_size,
                              hipStream_t stream) {
    const float* x    = (const float*)d_in[0];
    const int*   ei   = (const int*)d_in[1];
    const float* ea   = (const float*)d_in[2];
    const float* Wl1  = (const float*)d_in[3];
    const float* bl1  = (const float*)d_in[4];
    const float* Wr1  = (const float*)d_in[5];
    const float* br1  = (const float*)d_in[6];
    const float* We1  = (const float*)d_in[7];
    const float* att1 = (const float*)d_in[8];
    const float* bo1  = (const float*)d_in[9];
    const float* Wl2  = (const float*)d_in[10];
    const float* bl2  = (const float*)d_in[11];
    const float* Wr2  = (const float*)d_in[12];
    const float* br2  = (const float*)d_in[13];
    const float* We2  = (const float*)d_in[14];
    const float* att2 = (const float*)d_in[15];
    const float* bo2  = (const float*)d_in[16];
    const float* Wsk  = (const float*)d_in[17];
    const float* bsk  = (const float*)d_in[18];
    float* out = (float*)d_out;

    const int N = in_sizes[0] / DCH;
    const int E = in_sizes[1] / 2;

    // workspace layout (floats/ints, 4B units)
    char* ws = (char*)d_ws;
    size_t off = 0;
    float* xl   = (float*)(ws + off); off += (size_t)N * DCH * 4;
    float* xr   = (float*)(ws + off); off += (size_t)N * DCH * 4;
    float* h    = (float*)(ws + off); off += (size_t)N * DCH * 4;
    float* S    = (float*)(ws + off); off += (size_t)N * DCH * 4;
    float* es   = (float*)(ws + off); off += (size_t)E * 4;
    int* rowptr = (int*)(ws + off);   off += (size_t)(N + 1) * 4;
    int* degcnt = (int*)(ws + off);   off += (size_t)(2 * N) * 4;   // deg | cnt
    int* csrc   = (int*)(ws + off);   off += (size_t)E * 4;
    int* ceid   = (int*)(ws + off);   off += (size_t)E * 4;
    int* bsum   = (int*)(ws + off);   off += 256 * 4;
    int* deg = degcnt;
    int* cnt = degcnt + N;

    const int nb = (N + 1023) / 1024;

    // ---- CSR build ----
    k_zero<<<(2 * N + 255) / 256, 256, 0, stream>>>(degcnt, 2 * N);
    k_count<<<(E + 255) / 256, 256, 0, stream>>>(ei, deg, E);
    k_scan1<<<nb, 256, 0, stream>>>(deg, rowptr, bsum, N);
    k_scan2<<<1, 1, 0, stream>>>(bsum, nb);
    k_scan3<<<(N + 255) / 256, 256, 0, stream>>>(rowptr, bsum, N, E);
    k_fill<<<(E + 255) / 256, 256, 0, stream>>>(ei, rowptr, cnt, csrc, ceid, E);

    const int node_tiles = (N + 63) / 64;
    const int ng_blocks = (node_tiles + 3) / 4;
    const int eg_blocks = (E + 255) / 256;   // 4 waves/block, 64 edges/wave
    const int pull_blocks = (N + 3) / 4;

    // ---- layer 1 ----
    k_node_gemm<<<ng_blocks, 256, 0, stream>>>(x, N,
        Wl1, bl1, xl, Wr1, br1, xr, Wsk, bsk, S);
    k_edge_score<<<eg_blocks, 256, 0, stream>>>(ea, ei, We1, att1, xl, xr, es, E);
    k_pull<<<pull_blocks, 256, 0, stream>>>(rowptr, csrc, ceid, es, xl, bo1,
                                            nullptr, h, N);
    // ---- layer 2 ----
    k_node_gemm<<<ng_blocks, 256, 0, stream>>>(h, N,
        Wl2, bl2, xl, Wr2, br2, xr, nullptr, nullptr, nullptr);
    k_edge_score<<<eg_blocks, 256, 0, stream>>>(ea, ei, We2, att2, xl, xr, es, E);
    k_pull<<<pull_blocks, 256, 0, stream>>>(rowptr, csrc, ceid, es, xl, bo2,
                                            S, out, N);
}

// Round 2
// 1299.377 us; speedup vs baseline: 1.0666x; 1.0666x over previous
//
#include <hip/hip_runtime.h>

#define DCH 64
#define NEG 0.2f

typedef float fx4 __attribute__((ext_vector_type(4)));
typedef short short8 __attribute__((ext_vector_type(8)));

__device__ __forceinline__ unsigned short f2bf(float f) {
    unsigned int u = __builtin_bit_cast(unsigned int, f);
    u += 0x7fffu + ((u >> 16) & 1u);   // round-to-nearest-even
    return (unsigned short)(u >> 16);
}
__device__ __forceinline__ float bf2f(unsigned short h) {
    unsigned int u = ((unsigned int)h) << 16;
    return __builtin_bit_cast(float, u);
}

__device__ __forceinline__ short8 pack_bf16x8(fx4 a, fx4 b) {
    short8 r;
    r[0] = (short)f2bf(a[0]); r[1] = (short)f2bf(a[1]);
    r[2] = (short)f2bf(a[2]); r[3] = (short)f2bf(a[3]);
    r[4] = (short)f2bf(b[0]); r[5] = (short)f2bf(b[1]);
    r[6] = (short)f2bf(b[2]); r[7] = (short)f2bf(b[3]);
    return r;
}

// ---------------- CSR build ----------------
__global__ void k_zero(int* __restrict__ p, int n) {
    int i = blockIdx.x * blockDim.x + threadIdx.x;
    if (i < n) p[i] = 0;
}

__global__ void k_count(const int* __restrict__ ei, int* __restrict__ deg, int E) {
    int e = blockIdx.x * blockDim.x + threadIdx.x;
    if (e < E) atomicAdd(&deg[ei[E + e]], 1);
}

__global__ void k_scan1(const int* __restrict__ deg, int* __restrict__ rowptr,
                        int* __restrict__ bsum, int n) {
    __shared__ int s[256];
    int t = threadIdx.x;
    int base = blockIdx.x * 1024 + t * 4;
    int v[4]; int sum = 0;
    #pragma unroll
    for (int j = 0; j < 4; j++) {
        int idx = base + j;
        v[j] = (idx < n) ? deg[idx] : 0;
        sum += v[j];
    }
    s[t] = sum;
    __syncthreads();
    for (int o = 1; o < 256; o <<= 1) {
        int add = (t >= o) ? s[t - o] : 0;
        __syncthreads();
        s[t] += add;
        __syncthreads();
    }
    int excl = s[t] - sum;
    if (t == 255) bsum[blockIdx.x] = s[255];
    int run = excl;
    #pragma unroll
    for (int j = 0; j < 4; j++) {
        int idx = base + j;
        if (idx < n) rowptr[idx] = run;
        run += v[j];
    }
}

__global__ void k_scan2(int* __restrict__ bsum, int nb) {
    int run = 0;
    for (int i = 0; i < nb; i++) { int t = bsum[i]; bsum[i] = run; run += t; }
}

__global__ void k_scan3(int* __restrict__ rowptr, const int* __restrict__ bsum,
                        int n, int E) {
    int i = blockIdx.x * blockDim.x + threadIdx.x;
    if (i < n) rowptr[i] += bsum[i >> 10];
    if (i == 0) rowptr[n] = E;
}

// fill CSR: csrc[p]=src, iperm[e]=p  (p = CSR slot of edge e)
__global__ void k_fill(const int* __restrict__ ei, const int* __restrict__ rowptr,
                       int* __restrict__ cnt, int* __restrict__ csrc,
                       int* __restrict__ iperm, int E) {
    int e = blockIdx.x * blockDim.x + threadIdx.x;
    if (e < E) {
        int t = ei[E + e];
        int p = rowptr[t] + atomicAdd(&cnt[t], 1);
        csrc[p] = ei[e];
        iperm[e] = p;
    }
}

// ---------------- node GEMM: xl(bf16) = X@Wl.T+bl ; xr(f32) = X@Wr.T+br ; opt S = X@Wsk.T+bsk
__global__ __launch_bounds__(256) void k_node_gemm(
    const float* __restrict__ X, int nrows,
    const float* __restrict__ Wl, const float* __restrict__ bl, unsigned short* __restrict__ XLB,
    const float* __restrict__ Wr, const float* __restrict__ br, float* __restrict__ XR,
    const float* __restrict__ Wsk, const float* __restrict__ bsk, float* __restrict__ S)
{
    int wid = (blockIdx.x * blockDim.x + threadIdx.x) >> 6;
    int lane = threadIdx.x & 63;
    int ntiles = (nrows + 63) >> 6;
    if (wid >= ntiles) return;
    int base = wid * 64;
    int l15 = lane & 15, q = lane >> 4;

    short8 afr[4][2];
    #pragma unroll
    for (int mt = 0; mt < 4; mt++) {
        int row = base + mt * 16 + l15;
        if (row >= nrows) row = nrows - 1;
        const float* xp = X + (size_t)row * DCH + q * 8;
        #pragma unroll
        for (int kt = 0; kt < 2; kt++) {
            fx4 v0 = *(const fx4*)(xp + kt * 32);
            fx4 v1 = *(const fx4*)(xp + kt * 32 + 4);
            afr[mt][kt] = pack_bf16x8(v0, v1);
        }
    }

    const float* Ws[3] = {Wl, Wr, Wsk};
    const float* bs[3] = {bl, br, bsk};
    int nmat = S ? 3 : 2;

    for (int m = 0; m < nmat; m++) {
        const float* W = Ws[m];
        short8 bfr[4][2];
        #pragma unroll
        for (int nt = 0; nt < 4; nt++) {
            const float* wp = W + (nt * 16 + l15) * DCH + q * 8;
            #pragma unroll
            for (int kt = 0; kt < 2; kt++) {
                fx4 v0 = *(const fx4*)(wp + kt * 32);
                fx4 v1 = *(const fx4*)(wp + kt * 32 + 4);
                bfr[nt][kt] = pack_bf16x8(v0, v1);
            }
        }
        fx4 acc[4][4] = {};
        #pragma unroll
        for (int kt = 0; kt < 2; kt++)
            #pragma unroll
            for (int mt = 0; mt < 4; mt++)
                #pragma unroll
                for (int nt = 0; nt < 4; nt++)
                    acc[mt][nt] = __builtin_amdgcn_mfma_f32_16x16x32_bf16(
                        afr[mt][kt], bfr[nt][kt], acc[mt][nt], 0, 0, 0);

        float bias[4];
        #pragma unroll
        for (int nt = 0; nt < 4; nt++) bias[nt] = bs[m][nt * 16 + l15];
        // C/D layout: row = q*4 + r (+16*mt), col = l15 (+16*nt)
        #pragma unroll
        for (int mt = 0; mt < 4; mt++) {
            #pragma unroll
            for (int r = 0; r < 4; r++) {
                int row = base + mt * 16 + q * 4 + r;
                if (row < nrows) {
                    #pragma unroll
                    for (int nt = 0; nt < 4; nt++) {
                        float v = acc[mt][nt][r] + bias[nt];
                        if (m == 0)
                            XLB[(size_t)row * DCH + nt * 16 + l15] = f2bf(v);
                        else if (m == 1)
                            XR[(size_t)row * DCH + nt * 16 + l15] = v;
                        else
                            S[(size_t)row * DCH + nt * 16 + l15] = v;
                    }
                }
            }
        }
    }
}

// ---------------- edge transform (both layers): e_l[iperm[e]] = bf16(EA[e] @ Wel.T)
__global__ __launch_bounds__(256) void k_edge_tf(
    const float* __restrict__ EA, const int* __restrict__ iperm,
    const float* __restrict__ We1, const float* __restrict__ We2,
    unsigned short* __restrict__ E1, unsigned short* __restrict__ E2, int E)
{
    int wid = (blockIdx.x * blockDim.x + threadIdx.x) >> 6;
    int lane = threadIdx.x & 63;
    int l15 = lane & 15, q = lane >> 4;
    int base = wid * 64;
    if (base >= E) return;

    int p_me = iperm[min(base + lane, E - 1)];

    short8 afr[4][2];
    #pragma unroll
    for (int mt = 0; mt < 4; mt++) {
        int row = min(base + mt * 16 + l15, E - 1);
        const float* p = EA + (size_t)row * DCH + q * 8;
        #pragma unroll
        for (int kt = 0; kt < 2; kt++) {
            fx4 v0 = *(const fx4*)(p + kt * 32);
            fx4 v1 = *(const fx4*)(p + kt * 32 + 4);
            afr[mt][kt] = pack_bf16x8(v0, v1);
        }
    }

    const float* Ws[2] = {We1, We2};
    unsigned short* Es[2] = {E1, E2};
    #pragma unroll
    for (int lyr = 0; lyr < 2; lyr++) {
        const float* W = Ws[lyr];
        short8 bfr[4][2];
        #pragma unroll
        for (int nt = 0; nt < 4; nt++) {
            const float* wp = W + (nt * 16 + l15) * DCH + q * 8;
            #pragma unroll
            for (int kt = 0; kt < 2; kt++) {
                fx4 v0 = *(const fx4*)(wp + kt * 32);
                fx4 v1 = *(const fx4*)(wp + kt * 32 + 4);
                bfr[nt][kt] = pack_bf16x8(v0, v1);
            }
        }
        fx4 acc[4][4] = {};
        #pragma unroll
        for (int kt = 0; kt < 2; kt++)
            #pragma unroll
            for (int mt = 0; mt < 4; mt++)
                #pragma unroll
                for (int nt = 0; nt < 4; nt++)
                    acc[mt][nt] = __builtin_amdgcn_mfma_f32_16x16x32_bf16(
                        afr[mt][kt], bfr[nt][kt], acc[mt][nt], 0, 0, 0);

        unsigned short* Eo = Es[lyr];
        // edge m = mt*16 + q*4 + r lives in quad q; its channels = nt*16 + l15
        #pragma unroll
        for (int mt = 0; mt < 4; mt++) {
            #pragma unroll
            for (int r = 0; r < 4; r++) {
                int m = mt * 16 + q * 4 + r;
                int pm = __shfl(p_me, m);
                if (base + m < E) {
                    #pragma unroll
                    for (int nt = 0; nt < 4; nt++)
                        Eo[(size_t)pm * DCH + nt * 16 + l15] = f2bf(acc[mt][nt][r]);
                }
            }
        }
    }
}

// ---------------- fused pull: score + softmax + aggregate + bias + relu + norm
__global__ __launch_bounds__(256) void k_pull(
    const int* __restrict__ rowptr, const int* __restrict__ csrc,
    const unsigned short* __restrict__ ECSR, const unsigned short* __restrict__ XLB,
    const float* __restrict__ XR, const float* __restrict__ att,
    const float* __restrict__ bo, const float* __restrict__ skip,
    float* __restrict__ out, int n_nodes)
{
    int wid = (blockIdx.x * blockDim.x + threadIdx.x) >> 6;
    int lane = threadIdx.x & 63;
    if (wid >= n_nodes) return;
    int r0 = rowptr[wid], r1 = rowptr[wid + 1];
    float xr_l = XR[(size_t)wid * DCH + lane];
    float att_l = att[lane];
    float acc = 0.f, den = 0.f;

    for (int b = r0; b < r1; b += 64) {
        int cnt = min(64, r1 - b);
        int sj = 0;
        if (lane < cnt) sj = csrc[b + lane];
        // software pipeline: prefetch edge i+1's rows while reducing edge i
        int s0 = __shfl(sj, 0);
        unsigned short xl_pf = XLB[(size_t)s0 * DCH + lane];
        unsigned short e_pf = ECSR[(size_t)b * DCH + lane];
        for (int i = 0; i < cnt; i++) {
            float xlv = bf2f(xl_pf);
            float ev = bf2f(e_pf);
            if (i + 1 < cnt) {
                int s1 = __shfl(sj, i + 1);
                xl_pf = XLB[(size_t)s1 * DCH + lane];
                e_pf = ECSR[(size_t)(b + i + 1) * DCH + lane];
            }
            float z = xlv + xr_l + ev;
            float lr = fmaxf(z, 0.f) + NEG * fminf(z, 0.f);
            float t = att_l * lr;
            t += __shfl_xor(t, 1);
            t += __shfl_xor(t, 2);
            t += __shfl_xor(t, 4);
            t += __shfl_xor(t, 8);
            t += __shfl_xor(t, 16);
            t += __shfl_xor(t, 32);
            float w = __expf(t);
            acc = fmaf(w, xlv, acc);
            den += w;
        }
    }

    float v = acc / (den + 1e-16f) + bo[lane];
    if (skip) v += skip[(size_t)wid * DCH + lane];
    v = fmaxf(v, 0.f);
    float mu = v;
    #pragma unroll
    for (int o = 1; o < 64; o <<= 1) mu += __shfl_xor(mu, o);
    mu *= (1.f / 64.f);
    float d = v - mu;
    float var = d * d;
    #pragma unroll
    for (int o = 1; o < 64; o <<= 1) var += __shfl_xor(var, o);
    var *= (1.f / 64.f);
    out[(size_t)wid * DCH + lane] = d * rsqrtf(var + 1e-5f);
}

extern "C" void kernel_launch(void* const* d_in, const int* in_sizes, int n_in,
                              void* d_out, int out_size, void* d_ws, size_t ws_size,
                              hipStream_t stream) {
    const float* x    = (const float*)d_in[0];
    const int*   ei   = (const int*)d_in[1];
    const float* ea   = (const float*)d_in[2];
    const float* Wl1  = (const float*)d_in[3];
    const float* bl1  = (const float*)d_in[4];
    const float* Wr1  = (const float*)d_in[5];
    const float* br1  = (const float*)d_in[6];
    const float* We1  = (const float*)d_in[7];
    const float* att1 = (const float*)d_in[8];
    const float* bo1  = (const float*)d_in[9];
    const float* Wl2  = (const float*)d_in[10];
    const float* bl2  = (const float*)d_in[11];
    const float* Wr2  = (const float*)d_in[12];
    const float* br2  = (const float*)d_in[13];
    const float* We2  = (const float*)d_in[14];
    const float* att2 = (const float*)d_in[15];
    const float* bo2  = (const float*)d_in[16];
    const float* Wsk  = (const float*)d_in[17];
    const float* bsk  = (const float*)d_in[18];
    float* out = (float*)d_out;

    const int N = in_sizes[0] / DCH;
    const int E = in_sizes[1] / 2;

    char* ws = (char*)d_ws;
    size_t off = 0;
    unsigned short* e1  = (unsigned short*)(ws + off); off += (size_t)E * DCH * 2;
    unsigned short* e2  = (unsigned short*)(ws + off); off += (size_t)E * DCH * 2;
    unsigned short* xlb = (unsigned short*)(ws + off); off += (size_t)N * DCH * 2;
    float* xr   = (float*)(ws + off); off += (size_t)N * DCH * 4;
    float* h    = (float*)(ws + off); off += (size_t)N * DCH * 4;
    float* S    = (float*)(ws + off); off += (size_t)N * DCH * 4;
    int* rowptr = (int*)(ws + off);   off += (size_t)(N + 1) * 4;
    int* degcnt = (int*)(ws + off);   off += (size_t)(2 * N) * 4;
    int* csrc   = (int*)(ws + off);   off += (size_t)E * 4;
    int* iperm  = (int*)(ws + off);   off += (size_t)E * 4;
    int* bsum   = (int*)(ws + off);   off += 256 * 4;
    int* deg = degcnt;
    int* cnt = degcnt + N;

    const int nb = (N + 1023) / 1024;

    // ---- CSR build ----
    k_zero<<<(2 * N + 255) / 256, 256, 0, stream>>>(degcnt, 2 * N);
    k_count<<<(E + 255) / 256, 256, 0, stream>>>(ei, deg, E);
    k_scan1<<<nb, 256, 0, stream>>>(deg, rowptr, bsum, N);
    k_scan2<<<1, 1, 0, stream>>>(bsum, nb);
    k_scan3<<<(N + 255) / 256, 256, 0, stream>>>(rowptr, bsum, N, E);
    k_fill<<<(E + 255) / 256, 256, 0, stream>>>(ei, rowptr, cnt, csrc, iperm, E);

    const int node_tiles = (N + 63) / 64;
    const int ng_blocks = (node_tiles + 3) / 4;
    const int eg_blocks = (E / 64 + 3) / 4;
    const int pull_blocks = (N + 3) / 4;

    // ---- edge transforms for BOTH layers in one EA pass ----
    k_edge_tf<<<eg_blocks, 256, 0, stream>>>(ea, iperm, We1, We2, e1, e2, E);

    // ---- layer 1 ----
    k_node_gemm<<<ng_blocks, 256, 0, stream>>>(x, N, Wl1, bl1, xlb, Wr1, br1, xr,
                                               Wsk, bsk, S);
    k_pull<<<pull_blocks, 256, 0, stream>>>(rowptr, csrc, e1, xlb, xr, att1, bo1,
                                            nullptr, h, N);
    // ---- layer 2 ----
    k_node_gemm<<<ng_blocks, 256, 0, stream>>>(h, N, Wl2, bl2, xlb, Wr2, br2, xr,
                                               nullptr, nullptr, nullptr);
    k_pull<<<pull_blocks, 256, 0, stream>>>(rowptr, csrc, e2, xlb, xr, att2, bo2,
                                            S, out, N);
}

// Round 3
// 1201.130 us; speedup vs baseline: 1.1538x; 1.0818x over previous
//
#include <hip/hip_runtime.h>

#define DCH 64
#define NEG 0.2f

typedef float fx4 __attribute__((ext_vector_type(4)));
typedef short short8 __attribute__((ext_vector_type(8)));
typedef unsigned short us4 __attribute__((ext_vector_type(4)));

__device__ __forceinline__ unsigned short f2bf(float f) {
    unsigned int u = __builtin_bit_cast(unsigned int, f);
    u += 0x7fffu + ((u >> 16) & 1u);   // round-to-nearest-even
    return (unsigned short)(u >> 16);
}
__device__ __forceinline__ float bf2f(unsigned short h) {
    unsigned int u = ((unsigned int)h) << 16;
    return __builtin_bit_cast(float, u);
}

__device__ __forceinline__ short8 pack_bf16x8(fx4 a, fx4 b) {
    short8 r;
    r[0] = (short)f2bf(a[0]); r[1] = (short)f2bf(a[1]);
    r[2] = (short)f2bf(a[2]); r[3] = (short)f2bf(a[3]);
    r[4] = (short)f2bf(b[0]); r[5] = (short)f2bf(b[1]);
    r[6] = (short)f2bf(b[2]); r[7] = (short)f2bf(b[3]);
    return r;
}

// ---------------- CSR build ----------------
__global__ void k_zero(int* __restrict__ p, int n) {
    int i = blockIdx.x * blockDim.x + threadIdx.x;
    if (i < n) p[i] = 0;
}

__global__ void k_count(const int* __restrict__ ei, int* __restrict__ deg, int E) {
    int e = blockIdx.x * blockDim.x + threadIdx.x;
    if (e < E) atomicAdd(&deg[ei[E + e]], 1);
}

__global__ void k_scan1(const int* __restrict__ deg, int* __restrict__ rowptr,
                        int* __restrict__ bsum, int n) {
    __shared__ int s[256];
    int t = threadIdx.x;
    int base = blockIdx.x * 1024 + t * 4;
    int v[4]; int sum = 0;
    #pragma unroll
    for (int j = 0; j < 4; j++) {
        int idx = base + j;
        v[j] = (idx < n) ? deg[idx] : 0;
        sum += v[j];
    }
    s[t] = sum;
    __syncthreads();
    for (int o = 1; o < 256; o <<= 1) {
        int add = (t >= o) ? s[t - o] : 0;
        __syncthreads();
        s[t] += add;
        __syncthreads();
    }
    int excl = s[t] - sum;
    if (t == 255) bsum[blockIdx.x] = s[255];
    int run = excl;
    #pragma unroll
    for (int j = 0; j < 4; j++) {
        int idx = base + j;
        if (idx < n) rowptr[idx] = run;
        run += v[j];
    }
}

__global__ void k_scan2(int* __restrict__ bsum, int nb) {
    int run = 0;
    for (int i = 0; i < nb; i++) { int t = bsum[i]; bsum[i] = run; run += t; }
}

__global__ void k_scan3(int* __restrict__ rowptr, const int* __restrict__ bsum,
                        int n, int E) {
    int i = blockIdx.x * blockDim.x + threadIdx.x;
    if (i < n) rowptr[i] += bsum[i >> 10];
    if (i == 0) rowptr[n] = E;
}

// fill CSR: csrc[p]=src, iperm[e]=p
__global__ void k_fill(const int* __restrict__ ei, const int* __restrict__ rowptr,
                       int* __restrict__ cnt, int* __restrict__ csrc,
                       int* __restrict__ iperm, int E) {
    int e = blockIdx.x * blockDim.x + threadIdx.x;
    if (e < E) {
        int t = ei[E + e];
        int p = rowptr[t] + atomicAdd(&cnt[t], 1);
        csrc[p] = ei[e];
        iperm[e] = p;
    }
}

// ---------------- node GEMM: xl(bf16) = X@Wl.T+bl ; xr(f32) = X@Wr.T+br ; opt S
__global__ __launch_bounds__(256) void k_node_gemm(
    const float* __restrict__ X, int nrows,
    const float* __restrict__ Wl, const float* __restrict__ bl, unsigned short* __restrict__ XLB,
    const float* __restrict__ Wr, const float* __restrict__ br, float* __restrict__ XR,
    const float* __restrict__ Wsk, const float* __restrict__ bsk, float* __restrict__ S)
{
    int wid = (blockIdx.x * blockDim.x + threadIdx.x) >> 6;
    int lane = threadIdx.x & 63;
    int ntiles = (nrows + 63) >> 6;
    if (wid >= ntiles) return;
    int base = wid * 64;
    int l15 = lane & 15, q = lane >> 4;

    short8 afr[4][2];
    #pragma unroll
    for (int mt = 0; mt < 4; mt++) {
        int row = base + mt * 16 + l15;
        if (row >= nrows) row = nrows - 1;
        const float* xp = X + (size_t)row * DCH + q * 8;
        #pragma unroll
        for (int kt = 0; kt < 2; kt++) {
            fx4 v0 = *(const fx4*)(xp + kt * 32);
            fx4 v1 = *(const fx4*)(xp + kt * 32 + 4);
            afr[mt][kt] = pack_bf16x8(v0, v1);
        }
    }

    const float* Ws[3] = {Wl, Wr, Wsk};
    const float* bs[3] = {bl, br, bsk};
    int nmat = S ? 3 : 2;

    for (int m = 0; m < nmat; m++) {
        const float* W = Ws[m];
        short8 bfr[4][2];
        #pragma unroll
        for (int nt = 0; nt < 4; nt++) {
            const float* wp = W + (nt * 16 + l15) * DCH + q * 8;
            #pragma unroll
            for (int kt = 0; kt < 2; kt++) {
                fx4 v0 = *(const fx4*)(wp + kt * 32);
                fx4 v1 = *(const fx4*)(wp + kt * 32 + 4);
                bfr[nt][kt] = pack_bf16x8(v0, v1);
            }
        }
        fx4 acc[4][4] = {};
        #pragma unroll
        for (int kt = 0; kt < 2; kt++)
            #pragma unroll
            for (int mt = 0; mt < 4; mt++)
                #pragma unroll
                for (int nt = 0; nt < 4; nt++)
                    acc[mt][nt] = __builtin_amdgcn_mfma_f32_16x16x32_bf16(
                        afr[mt][kt], bfr[nt][kt], acc[mt][nt], 0, 0, 0);

        float bias[4];
        #pragma unroll
        for (int nt = 0; nt < 4; nt++) bias[nt] = bs[m][nt * 16 + l15];
        #pragma unroll
        for (int mt = 0; mt < 4; mt++) {
            #pragma unroll
            for (int r = 0; r < 4; r++) {
                int row = base + mt * 16 + q * 4 + r;
                if (row < nrows) {
                    #pragma unroll
                    for (int nt = 0; nt < 4; nt++) {
                        float v = acc[mt][nt][r] + bias[nt];
                        if (m == 0)
                            XLB[(size_t)row * DCH + nt * 16 + l15] = f2bf(v);
                        else if (m == 1)
                            XR[(size_t)row * DCH + nt * 16 + l15] = v;
                        else
                            S[(size_t)row * DCH + nt * 16 + l15] = v;
                    }
                }
            }
        }
    }
}

// ---------------- edge transform, TRANSPOSED output tile:
// D = We * EA^T  ->  lane holds 4 CONTIGUOUS channels of one edge -> ushort4 stores
__global__ __launch_bounds__(256) void k_edge_tf(
    const float* __restrict__ EA, const int* __restrict__ iperm,
    const float* __restrict__ We1, const float* __restrict__ We2,
    unsigned short* __restrict__ E1, unsigned short* __restrict__ E2, int E)
{
    int wid = (blockIdx.x * blockDim.x + threadIdx.x) >> 6;
    int lane = threadIdx.x & 63;
    int l15 = lane & 15, q = lane >> 4;
    int base = wid * 64;
    if (base >= E) return;

    int p_me = iperm[min(base + lane, E - 1)];

    // B fragments = EA^T: lane n=l15 -> edge row base+et*16+l15, k = q*8+j (+32*kt)
    short8 bfr[4][2];
    #pragma unroll
    for (int et = 0; et < 4; et++) {
        int row = min(base + et * 16 + l15, E - 1);
        const float* p = EA + (size_t)row * DCH + q * 8;
        #pragma unroll
        for (int kt = 0; kt < 2; kt++) {
            fx4 v0 = *(const fx4*)(p + kt * 32);
            fx4 v1 = *(const fx4*)(p + kt * 32 + 4);
            bfr[et][kt] = pack_bf16x8(v0, v1);
        }
    }

    const float* Ws[2] = {We1, We2};
    unsigned short* Es[2] = {E1, E2};
    #pragma unroll
    for (int lyr = 0; lyr < 2; lyr++) {
        const float* W = Ws[lyr];
        // A fragments = We: lane m=l15 -> out-ch row ct*16+l15, k = q*8+j (+32*kt)
        short8 afr[4][2];
        #pragma unroll
        for (int ct = 0; ct < 4; ct++) {
            const float* wp = W + (ct * 16 + l15) * DCH + q * 8;
            #pragma unroll
            for (int kt = 0; kt < 2; kt++) {
                fx4 v0 = *(const fx4*)(wp + kt * 32);
                fx4 v1 = *(const fx4*)(wp + kt * 32 + 4);
                afr[ct][kt] = pack_bf16x8(v0, v1);
            }
        }
        fx4 acc[4][4] = {};
        #pragma unroll
        for (int kt = 0; kt < 2; kt++)
            #pragma unroll
            for (int ct = 0; ct < 4; ct++)
                #pragma unroll
                for (int et = 0; et < 4; et++)
                    acc[ct][et] = __builtin_amdgcn_mfma_f32_16x16x32_bf16(
                        afr[ct][kt], bfr[et][kt], acc[ct][et], 0, 0, 0);

        unsigned short* Eo = Es[lyr];
        // acc[ct][et]: rows = out-ch ct*16 + q*4 + r, cols = edge base + et*16 + l15
        #pragma unroll
        for (int et = 0; et < 4; et++) {
            int pm = __shfl(p_me, et * 16 + l15);
            bool ok = (base + et * 16 + l15) < E;
            #pragma unroll
            for (int ct = 0; ct < 4; ct++) {
                us4 v;
                v[0] = f2bf(acc[ct][et][0]);
                v[1] = f2bf(acc[ct][et][1]);
                v[2] = f2bf(acc[ct][et][2]);
                v[3] = f2bf(acc[ct][et][3]);
                if (ok)
                    *(us4*)(Eo + (size_t)pm * DCH + ct * 16 + q * 4) = v;
            }
        }
    }
}

// ---------------- fused pull: 4 edge-slots x 16 channel-lanes per wave
__global__ __launch_bounds__(256) void k_pull(
    const int* __restrict__ rowptr, const int* __restrict__ csrc,
    const unsigned short* __restrict__ ECSR, const unsigned short* __restrict__ XLB,
    const float* __restrict__ XR, const float* __restrict__ att,
    const float* __restrict__ bo, const float* __restrict__ skip,
    float* __restrict__ out, int n_nodes)
{
    int wid = (blockIdx.x * blockDim.x + threadIdx.x) >> 6;
    int lane = threadIdx.x & 63;
    if (wid >= n_nodes) return;
    int g = lane >> 4;        // edge sub-slot 0..3
    int c = lane & 15;        // channel group: ch c*4 .. c*4+3
    int r0 = rowptr[wid], r1 = rowptr[wid + 1];

    fx4 xr4 = *(const fx4*)(XR + (size_t)wid * DCH + c * 4);
    fx4 at4 = *(const fx4*)(att + c * 4);
    fx4 acc = {0.f, 0.f, 0.f, 0.f};
    float den = 0.f;

    for (int b = r0; b < r1; b += 4) {
        int slot = b + g;
        bool valid = slot < r1;
        int sl = valid ? slot : (r1 - 1);
        int src = csrc[sl];
        us4 xl4 = *(const us4*)(XLB + (size_t)src * DCH + c * 4);
        us4 e4  = *(const us4*)(ECSR + (size_t)sl * DCH + c * 4);
        float xv[4]; float p = 0.f;
        #pragma unroll
        for (int i = 0; i < 4; i++) {
            xv[i] = bf2f(xl4[i]);
            float z = xv[i] + xr4[i] + bf2f(e4[i]);
            float lr = fmaxf(z, 0.f) + NEG * fminf(z, 0.f);
            p = fmaf(at4[i], lr, p);
        }
        p += __shfl_xor(p, 1);
        p += __shfl_xor(p, 2);
        p += __shfl_xor(p, 4);
        p += __shfl_xor(p, 8);
        float w = valid ? __expf(p) : 0.f;
        #pragma unroll
        for (int i = 0; i < 4; i++) acc[i] = fmaf(w, xv[i], acc[i]);
        den += w;
    }

    // combine the 4 edge-slot groups
    #pragma unroll
    for (int i = 0; i < 4; i++) {
        acc[i] += __shfl_xor(acc[i], 16);
        acc[i] += __shfl_xor(acc[i], 32);
    }
    den += __shfl_xor(den, 16);
    den += __shfl_xor(den, 32);

    float inv = 1.f / (den + 1e-16f);
    float v[4]; float s = 0.f;
    fx4 sk4 = {0.f, 0.f, 0.f, 0.f};
    if (skip) sk4 = *(const fx4*)(skip + (size_t)wid * DCH + c * 4);
    fx4 bo4 = *(const fx4*)(bo + c * 4);
    #pragma unroll
    for (int i = 0; i < 4; i++) {
        v[i] = acc[i] * inv + bo4[i] + sk4[i];
        v[i] = fmaxf(v[i], 0.f);
        s += v[i];
    }
    s += __shfl_xor(s, 1); s += __shfl_xor(s, 2);
    s += __shfl_xor(s, 4); s += __shfl_xor(s, 8);
    float mu = s * (1.f / 64.f);
    float ss = 0.f;
    #pragma unroll
    for (int i = 0; i < 4; i++) { v[i] -= mu; ss += v[i] * v[i]; }
    ss += __shfl_xor(ss, 1); ss += __shfl_xor(ss, 2);
    ss += __shfl_xor(ss, 4); ss += __shfl_xor(ss, 8);
    float rs = rsqrtf(ss * (1.f / 64.f) + 1e-5f);
    if (g == 0) {
        fx4 o;
        #pragma unroll
        for (int i = 0; i < 4; i++) o[i] = v[i] * rs;
        *(fx4*)(out + (size_t)wid * DCH + c * 4) = o;
    }
}

extern "C" void kernel_launch(void* const* d_in, const int* in_sizes, int n_in,
                              void* d_out, int out_size, void* d_ws, size_t ws_size,
                              hipStream_t stream) {
    const float* x    = (const float*)d_in[0];
    const int*   ei   = (const int*)d_in[1];
    const float* ea   = (const float*)d_in[2];
    const float* Wl1  = (const float*)d_in[3];
    const float* bl1  = (const float*)d_in[4];
    const float* Wr1  = (const float*)d_in[5];
    const float* br1  = (const float*)d_in[6];
    const float* We1  = (const float*)d_in[7];
    const float* att1 = (const float*)d_in[8];
    const float* bo1  = (const float*)d_in[9];
    const float* Wl2  = (const float*)d_in[10];
    const float* bl2  = (const float*)d_in[11];
    const float* Wr2  = (const float*)d_in[12];
    const float* br2  = (const float*)d_in[13];
    const float* We2  = (const float*)d_in[14];
    const float* att2 = (const float*)d_in[15];
    const float* bo2  = (const float*)d_in[16];
    const float* Wsk  = (const float*)d_in[17];
    const float* bsk  = (const float*)d_in[18];
    float* out = (float*)d_out;

    const int N = in_sizes[0] / DCH;
    const int E = in_sizes[1] / 2;

    char* ws = (char*)d_ws;
    size_t off = 0;
    unsigned short* e1  = (unsigned short*)(ws + off); off += (size_t)E * DCH * 2;
    unsigned short* e2  = (unsigned short*)(ws + off); off += (size_t)E * DCH * 2;
    unsigned short* xlb = (unsigned short*)(ws + off); off += (size_t)N * DCH * 2;
    float* xr   = (float*)(ws + off); off += (size_t)N * DCH * 4;
    float* h    = (float*)(ws + off); off += (size_t)N * DCH * 4;
    float* S    = (float*)(ws + off); off += (size_t)N * DCH * 4;
    int* rowptr = (int*)(ws + off);   off += (size_t)(N + 1) * 4;
    int* degcnt = (int*)(ws + off);   off += (size_t)(2 * N) * 4;
    int* csrc   = (int*)(ws + off);   off += (size_t)E * 4;
    int* iperm  = (int*)(ws + off);   off += (size_t)E * 4;
    int* bsum   = (int*)(ws + off);   off += 256 * 4;
    int* deg = degcnt;
    int* cnt = degcnt + N;

    const int nb = (N + 1023) / 1024;

    // ---- CSR build ----
    k_zero<<<(2 * N + 255) / 256, 256, 0, stream>>>(degcnt, 2 * N);
    k_count<<<(E + 255) / 256, 256, 0, stream>>>(ei, deg, E);
    k_scan1<<<nb, 256, 0, stream>>>(deg, rowptr, bsum, N);
    k_scan2<<<1, 1, 0, stream>>>(bsum, nb);
    k_scan3<<<(N + 255) / 256, 256, 0, stream>>>(rowptr, bsum, N, E);
    k_fill<<<(E + 255) / 256, 256, 0, stream>>>(ei, rowptr, cnt, csrc, iperm, E);

    const int node_tiles = (N + 63) / 64;
    const int ng_blocks = (node_tiles + 3) / 4;
    const int eg_blocks = ((E + 63) / 64 + 3) / 4;
    const int pull_blocks = (N + 3) / 4;

    // ---- edge transforms for BOTH layers in one EA pass ----
    k_edge_tf<<<eg_blocks, 256, 0, stream>>>(ea, iperm, We1, We2, e1, e2, E);

    // ---- layer 1 ----
    k_node_gemm<<<ng_blocks, 256, 0, stream>>>(x, N, Wl1, bl1, xlb, Wr1, br1, xr,
                                               Wsk, bsk, S);
    k_pull<<<pull_blocks, 256, 0, stream>>>(rowptr, csrc, e1, xlb, xr, att1, bo1,
                                            nullptr, h, N);
    // ---- layer 2 ----
    k_node_gemm<<<ng_blocks, 256, 0, stream>>>(h, N, Wl2, bl2, xlb, Wr2, br2, xr,
                                               nullptr, nullptr, nullptr);
    k_pull<<<pull_blocks, 256, 0, stream>>>(rowptr, csrc, e2, xlb, xr, att2, bo2,
                                            S, out, N);
}